// Round 5
// baseline (316.957 us; speedup 1.0000x reference)
//
#include <hip/hip_runtime.h>
#include <cstdint>
#include <cstddef>

// ONLSTM cell: B=4096, D=1024, U=1024.
// pre16 = fp16([X|H] @ [[W_all],[U_all]] + b_all), single-fp16 MFMA.
// R1-R6 history: absmax (0.25) dominated by fp32 softmax/cumsum path; threshold 1.55.
// R8: 8-phase/counted-vmcnt: 123us, MfmaUtil 37%.
// R9: triple-ring BK=64, 1 barrier/tile: 109us, MfmaUtil 42%, 1 blk/CU (LDS 144KB).
// R10: BK=32 ring, 2 blk/CU: 116.8us — occupancy 36% ✓ but 12.58M bank conflicts:
//      slot^=(r&3) swizzle collides (64B row = 8 bank-quads; quad(r)=4*(r&1)+slot;
//      r and r+4 alias). Conflict stall ~20us ate the occupancy win.
// R11 (this round):
//   1. swizzle fixed to slot ^= (r>>1)&3  -> quad = 4*(r&1) + (kgrp^((r>>1)&3)),
//      bijective over any 8 consecutive rows per kgrp (enumerated), 2 lanes/quad
//      over 16 rows = b128 floor. Same involution on stage-source and read ->
//      bit-identical numerics.
//   2. onlstm_final: libm tanhf -> (e-1)*rcp(e+1), e=__expf(2x) clamped; sigmoid
//      divisions -> v_rcp_f32. Abs err ~1e-7, threshold 1.55.

typedef _Float16 half8  __attribute__((ext_vector_type(8)));
typedef _Float16 half4v __attribute__((ext_vector_type(4)));
typedef float f32x4 __attribute__((ext_vector_type(4)));

__device__ __forceinline__ void async16(const _Float16* g, _Float16* l) {
  __builtin_amdgcn_global_load_lds(
      (const __attribute__((address_space(1))) void*)g,
      (__attribute__((address_space(3))) void*)l, 16, 0, 0);
}

struct Ptrs12 { const float* p[12]; };
struct Ptrs6  { const float* p[6];  };

// ---------------------------------------------------------------------------
// Merged prep: convert A (X|H -> fp16), convert+transpose B (x64 scale, fp16),
// build bias. Branch is block-uniform. (unchanged from R6)
__global__ void prep(const float* __restrict__ X, const float* __restrict__ H,
                     Ptrs12 w, Ptrs6 bs,
                     _Float16* __restrict__ Ahi, _Float16* __restrict__ Bhi,
                     float* __restrict__ b_all) {
  __shared__ float tile[64][65];
  const int blk = blockIdx.x;
  const int t = threadIdx.x;
  if (blk < 8192) {
    size_t base = ((size_t)blk * 256 + t) * 4;
    int k = (int)(base & 2047);
    size_t b = base >> 11;
    const float* src = (k < 1024) ? (X + b * 1024 + k) : (H + b * 1024 + (k - 1024));
    float4 v = *(const float4*)src;
    half4v hi = { (_Float16)v.x, (_Float16)v.y, (_Float16)v.z, (_Float16)v.w };
    *(half4v*)(Ahi + base) = hi;
  } else if (blk < 11264) {
    int bb = blk - 8192;
    int mat = bb >> 8;
    int tl = bb & 255;
    int tr = tl >> 4, tc = tl & 15;
    int g = mat >> 1, s = mat & 1;
    const float* src = w.p[mat];
    int col = t & 63, r0 = t >> 6;
#pragma unroll
    for (int i = 0; i < 16; i++) {
      int row = i * 4 + r0;
      tile[row][col] = src[(size_t)(tr * 64 + row) * 1024 + tc * 64 + col];
    }
    __syncthreads();
    int c2 = t >> 2, kseg = t & 3;
    half8 v0, v1;
#pragma unroll
    for (int j = 0; j < 8; j++) {
      v0[j] = (_Float16)(tile[kseg * 16 + j][c2] * 64.0f);
      v1[j] = (_Float16)(tile[kseg * 16 + 8 + j][c2] * 64.0f);
    }
    size_t n  = (size_t)g * 1024 + tc * 64 + c2;
    size_t kk = (size_t)s * 1024 + tr * 64 + kseg * 16;
    *(half8*)(Bhi + n * 2048 + kk) = v0;
    *(half8*)(Bhi + n * 2048 + kk + 8) = v1;
  } else {
    int n = (blk - 11264) * 256 + t;
    b_all[n] = bs.p[n >> 10][n & 1023];
  }
}

// ---------------------------------------------------------------------------
// GEMM: A[4096,2048] @ Bt[6144,2048]^T / 64 + bias -> pre16 (fp16, row-major).
// Triple-buffer ring BK=32, 2 blocks/CU, fixed swizzle; see header comment.

#define LGKM0 asm volatile("s_waitcnt lgkmcnt(0)" ::: "memory")

__device__ __forceinline__ void wg_barrier() {
  __builtin_amdgcn_s_barrier();
  asm volatile("" ::: "memory");
}

__global__ __launch_bounds__(512, 4) void gemm_ring32(
    const _Float16* __restrict__ Ah, const _Float16* __restrict__ Bh,
    const float* __restrict__ b_all, _Float16* __restrict__ pre16) {
  // 3 bufs x 12288 halfs (A 4096 + B 8192) = 72 KB. Epilogue reuses 66 KB.
  __shared__ __attribute__((aligned(16))) _Float16 lds[36864];

  // Bijective XCD swizzle: 768 blocks = 8 XCDs x 96. Within a chunk: B-panel
  // major (nTile constant over 32 consecutive blocks -> 1 MB B panel hot in L2).
  const int bid = blockIdx.x;
  const int swz = (bid & 7) * 96 + (bid >> 3);
  const int nTile = swz / 32;   // 0..23
  const int mTile = swz % 32;   // 0..31

  const int t = threadIdx.x;
  const int lane = t & 63;
  const int wave = t >> 6;
  const int wm = wave >> 2, wn = wave & 3;       // 2 x 4 waves; per-wave 64x64
  const int kgrp = lane >> 4, frow = lane & 15;

  const _Float16* Abase = Ah + (size_t)mTile * 128 * 2048;
  const _Float16* Bbase = Bh + (size_t)nTile * 256 * 2048;

  f32x4 acc[4][4] = {};

  // Stage one K-tile (A 128x32 = 8KB -> 1 load/thr; B 256x32 = 16KB -> 2).
  // LDS dest linear (wave-uniform base + lane*16); 2-bit XOR slot swizzle
  // slot ^= (r>>1)&3 folded into the GLOBAL source address. Bank-quad of the
  // 16B unit = 4*(r&1) + slot_phys -> bijective per 8 consecutive rows.
  auto stage_tile = [&](int kt, int base) {
    {
      int r = t >> 2, sl = t & 3;
      int xs = sl ^ ((r >> 1) & 3);
      async16(Abase + (size_t)r * 2048 + kt * 32 + xs * 8, lds + base + t * 8);
    }
#pragma unroll
    for (int q = 0; q < 2; q++) {
      int s = q * 512 + t;
      int r = s >> 2, sl = s & 3;
      int xs = sl ^ ((r >> 1) & 3);
      async16(Bbase + (size_t)r * 2048 + kt * 32 + xs * 8,
              lds + base + 4096 + s * 8);
    }
  };

  // Rotating ring offsets (in halfs).
  int cur = 0, nxt = 12288, nn = 24576;

  // Prologue: stage tiles 0,1 (3 loads each). vmcnt(3) -> tile0 landed.
  stage_tile(0, cur);
  stage_tile(1, nxt);
  asm volatile("s_waitcnt vmcnt(3)" ::: "memory");
  wg_barrier();

  for (int T = 0; T < 64; T++) {
    // ds_read this tile's 8 fragments (conflict-free permutation of 1KB rows).
    const _Float16* A_ = lds + cur;
    const _Float16* B_ = lds + cur + 4096;
    half8 af[4], bf[4];
#pragma unroll
    for (int mi = 0; mi < 4; mi++) {
      int r = wm * 64 + mi * 16 + frow;
      af[mi] = *(const half8*)(A_ + r * 32 + ((kgrp ^ ((r >> 1) & 3)) * 8));
    }
#pragma unroll
    for (int nj = 0; nj < 4; nj++) {
      int r = wn * 64 + nj * 16 + frow;
      bf[nj] = *(const half8*)(B_ + r * 32 + ((kgrp ^ ((r >> 1) & 3)) * 8));
    }
    // Stage tile T+2 into the ring slot last read at iter T-1 (distance-2).
    if (T + 2 < 64) stage_tile(T + 2, nn);

    // Drain my ds_reads (buf(cur) overwrite-safe once all waves pass barrier);
    // vmcnt(3): tile T+1 proven landed, T+2's 3 loads stay in flight.
    LGKM0;
    if (T < 62) {
      asm volatile("s_waitcnt vmcnt(3)" ::: "memory");
      wg_barrier();
    } else if (T == 62) {
      asm volatile("s_waitcnt vmcnt(0)" ::: "memory");
      wg_barrier();
    }
    // T==63: nothing outstanding; epilogue __syncthreads covers the handoff.

    // MFMA cluster AFTER the barrier: next iteration's ds_reads (and the
    // other resident block's waves) overlap it.
    __builtin_amdgcn_s_setprio(1);
#pragma unroll
    for (int mi = 0; mi < 4; mi++)
#pragma unroll
      for (int nj = 0; nj < 4; nj++)
        acc[mi][nj] = __builtin_amdgcn_mfma_f32_16x16x32_f16(
            af[mi], bf[nj], acc[mi][nj], 0, 0, 0);
    __builtin_amdgcn_s_setprio(0);

    int tmp = cur; cur = nxt; nxt = nn; nn = tmp;
  }

  // Epilogue: stage fp16 C-tile [128][264] (padded) in LDS, then coalesced
  // half8 stores. __syncthreads() drains lgkm+vm and fences all waves' reads
  // of the last ring buffer before overwrite.
  __syncthreads();
  const float inv64 = 1.0f / 64.0f;
  const int cb = nTile * 256;
  float bias[4];
#pragma unroll
  for (int nj = 0; nj < 4; nj++)
    bias[nj] = b_all[cb + wn * 64 + nj * 16 + frow];
#pragma unroll
  for (int mi = 0; mi < 4; mi++) {
#pragma unroll
    for (int nj = 0; nj < 4; nj++) {
      int row = wm * 64 + mi * 16 + kgrp * 4;
      int col = wn * 64 + nj * 16 + frow;
#pragma unroll
      for (int j = 0; j < 4; j++)
        lds[(row + j) * 264 + col] =
            (_Float16)(acc[mi][nj][j] * inv64 + bias[nj]);
    }
  }
  __syncthreads();
#pragma unroll
  for (int rr = 0; rr < 8; rr++) {
    int L = rr * 4096 + t * 8;
    int row = L >> 8, col = L & 255;
    half8 v = *(const half8*)(lds + row * 264 + col);
    *(half8*)(pre16 + (size_t)(mTile * 128 + row) * 6144 + cb + col) = v;
  }
}

// ---------------------------------------------------------------------------
// Row softmax over zft/zit (fp16 in pre16, cols 4096..6143), p written back in
// place (fp16) + per-chunk column sums into transposed part4. (unchanged)
__global__ void softmax_partials(_Float16* __restrict__ pre16, f32x4* __restrict__ part4) {
  __shared__ float wsum[4][1024];
  int m = blockIdx.x >> 9;
  int ch = blockIdx.x & 511;
  int t = threadIdx.x;
  int wave = t >> 6, lane = t & 63;
  f32x4 colacc[4] = {};
  for (int rr = 0; rr < 2; rr++) {
    int b = ch * 8 + wave * 2 + rr;
    _Float16* row = pre16 + (size_t)b * 6144 + (4 + m) * 1024;
    f32x4 v[4];
    float mx = -3.4e38f;
#pragma unroll
    for (int j = 0; j < 4; j++) {
      half4v h = *(const half4v*)(row + lane * 4 + 256 * j);
      v[j] = f32x4{ (float)h[0], (float)h[1], (float)h[2], (float)h[3] };
      mx = fmaxf(mx, fmaxf(fmaxf(v[j][0], v[j][1]), fmaxf(v[j][2], v[j][3])));
    }
#pragma unroll
    for (int off = 32; off > 0; off >>= 1) mx = fmaxf(mx, __shfl_xor(mx, off, 64));
    float sum = 0.f;
#pragma unroll
    for (int j = 0; j < 4; j++)
#pragma unroll
      for (int q = 0; q < 4; q++) { v[j][q] = __expf(v[j][q] - mx); sum += v[j][q]; }
#pragma unroll
    for (int off = 32; off > 0; off >>= 1) sum += __shfl_xor(sum, off, 64);
    float inv = 1.f / sum;
#pragma unroll
    for (int j = 0; j < 4; j++) {
      v[j] *= inv;
      half4v h = { (_Float16)v[j][0], (_Float16)v[j][1], (_Float16)v[j][2], (_Float16)v[j][3] };
      *(half4v*)(row + lane * 4 + 256 * j) = h;
      colacc[j] += v[j];
    }
  }
#pragma unroll
  for (int j = 0; j < 4; j++)
    *(f32x4*)(&wsum[wave][lane * 4 + 256 * j]) = colacc[j];
  __syncthreads();
  f32x4 s = *(const f32x4*)(&wsum[0][t * 4]);
  s += *(const f32x4*)(&wsum[1][t * 4]);
  s += *(const f32x4*)(&wsum[2][t * 4]);
  s += *(const f32x4*)(&wsum[3][t * 4]);
  part4[((size_t)m * 256 + t) * 512 + ch] = s;
}

// Exclusive scan over 512 chunks per (m, c4-group). (unchanged)
__global__ void scan_partials(const f32x4* __restrict__ part4, f32x4* __restrict__ off4) {
  int gidx = blockIdx.x * 4 + (threadIdx.x >> 6);
  int lane = threadIdx.x & 63;
  size_t base = (size_t)gidx * 512;
  f32x4 v[8];
  f32x4 s = {};
#pragma unroll
  for (int j = 0; j < 8; j++) {
    v[j] = part4[base + lane * 8 + j];
    s += v[j];
  }
  f32x4 incl = s;
#pragma unroll
  for (int off = 1; off < 64; off <<= 1) {
    f32x4 o;
#pragma unroll
    for (int q = 0; q < 4; q++) o[q] = __shfl_up(incl[q], off, 64);
    if (lane >= off) incl += o;
  }
  f32x4 run = incl - s;
#pragma unroll
  for (int j = 0; j < 8; j++) {
    off4[base + lane * 8 + j] = run;
    run += v[j];
  }
}

// Final: gates + cumsum + cell/hidden. R11: fast transcendentals —
// sigmoid via v_rcp_f32, tanh via (e-1)*rcp(e+1), e=__expf(2x) clamped ±15
// (no overflow: e <= e^30 ~ 1e13). Abs err ~1e-7 vs threshold 1.55.
__device__ __forceinline__ float fast_sigmoid(float x) {
  return __builtin_amdgcn_rcpf(1.f + __expf(-x));
}
__device__ __forceinline__ float fast_tanh(float x) {
  float xc = fminf(fmaxf(x, -15.f), 15.f);
  float e = __expf(2.f * xc);
  return (e - 1.f) * __builtin_amdgcn_rcpf(e + 1.f);
}

__global__ void onlstm_final(const _Float16* __restrict__ pre16,
                             const float* __restrict__ cprev, const f32x4* __restrict__ off4,
                             float* __restrict__ out) {
  int ch = blockIdx.x;
  int c4 = threadIdx.x;
  int c = c4 * 4;
  f32x4 runf = off4[(size_t)c4 * 512 + ch];
  f32x4 runi = off4[(size_t)(256 + c4) * 512 + ch];
  for (int r = 0; r < 8; r++) {
    int b = ch * 8 + r;
    const _Float16* row = pre16 + (size_t)b * 6144;
    half4v zf = *(const half4v*)(row + c);
    half4v zi = *(const half4v*)(row + 1024 + c);
    half4v zo = *(const half4v*)(row + 2048 + c);
    half4v zc = *(const half4v*)(row + 3072 + c);
    half4v pf = *(const half4v*)(row + 4096 + c);
    half4v pi = *(const half4v*)(row + 5120 + c);
    f32x4 cp = *(const f32x4*)(cprev + (size_t)b * 1024 + c);
    f32x4 hid, cel;
#pragma unroll
    for (int q = 0; q < 4; q++) {
      runf[q] += (float)pf[q];
      runi[q] += (float)pi[q];
      float ft = runf[q], it = 1.f - runi[q];
      float f  = fast_sigmoid((float)zf[q]);
      float ii = fast_sigmoid((float)zi[q]);
      float o  = fast_sigmoid((float)zo[q]);
      float chat = fast_tanh((float)zc[q]);
      float omega = ft * it;
      float fhat = f * omega + (ft - omega);
      float ihat = ii * omega + (it - omega);
      float cell = fhat * cp[q] + ihat * chat;
      hid[q] = o * fast_tanh(cell);
      cel[q] = cell;
    }
    *(f32x4*)(out + (size_t)b * 1024 + c) = hid;
    *(f32x4*)(out + (size_t)4194304 + (size_t)b * 1024 + c) = cel;
  }
}

// ---------------------------------------------------------------------------
extern "C" void kernel_launch(void* const* d_in, const int* in_sizes, int n_in,
                              void* d_out, int out_size, void* d_ws, size_t ws_size,
                              hipStream_t stream) {
  const float* X = (const float*)d_in[0];
  const float* H = (const float*)d_in[1];
  const float* C = (const float*)d_in[2];

  char* ws = (char*)d_ws;
  _Float16* pre16 = (_Float16*)(ws);                      // 48 MB [4096][6144]
  _Float16* Ahi   = (_Float16*)(ws + 50331648);           // 16 MB
  _Float16* Bhi   = (_Float16*)(ws + 67108864);           // 24 MB
  float*    b_all = (float*)(ws + 92274688);              // 24 KB
  f32x4*    part4 = (f32x4*)(ws + 92299264);              //  4 MB
  f32x4*    off4  = (f32x4*)(ws + 96493568);              //  4 MB

  Ptrs12 w;
  for (int g = 0; g < 6; g++) {
    w.p[2 * g]     = (const float*)d_in[3 + 3 * g];
    w.p[2 * g + 1] = (const float*)d_in[4 + 3 * g];
  }
  Ptrs6 bs;
  for (int g = 0; g < 6; g++) bs.p[g] = (const float*)d_in[5 + 3 * g];

  prep<<<11288, 256, 0, stream>>>(X, H, w, bs, Ahi, Bhi, b_all);
  gemm_ring32<<<768, 512, 0, stream>>>(Ahi, Bhi, b_all, pre16);
  softmax_partials<<<1024, 256, 0, stream>>>(pre16, part4);
  scan_partials<<<128, 256, 0, stream>>>(part4, off4);
  onlstm_final<<<512, 256, 0, stream>>>(pre16, C, off4, (float*)d_out);
}

// Round 6
// 304.020 us; speedup vs baseline: 1.0426x; 1.0426x over previous
//
#include <hip/hip_runtime.h>
#include <cstdint>
#include <cstddef>

// ONLSTM cell: B=4096, D=1024, U=1024.
// pre16 = fp16([X|H] @ [[W_all],[U_all]] + b_all), single-fp16 MFMA.
// R1-R6: absmax (0.25) dominated by fp32 softmax/cumsum path; threshold 1.55.
// R8 123us / R9 109 / R10 116.8 / R11 118.8 — four different schedules all
// ~110-120us, each ~2x above every pipe ceiling (MFMA 25us, LDS 63us, HBM 31us)
// with MfmaUtil+VALUBusy ~60% => serial-chain-bound, not bandwidth-bound.
// R12 (this round): 256x256 tile, BK=32, wave=128x64 (acc 128 AGPR):
//   - 43.7 FLOP per LDS-read byte (vs 32), 2x FLOP per barrier.
//   - ring-3 x 32KB = 96KB, dist-2 staging, vmcnt(4) steady (never 0 till T=62).
//   - split-MFMA pipeline: per tile, MFMA mi0-3; vmcnt+barrier (proves buf T+1);
//     ds_read A(T+1)[0..3] into freed regs; MFMA mi4-7 (hides read latency);
//     ds_read A(T+1)[4..7]+B(T+1); loop-top lgkm0. LDS-read era overlaps MFMA
//     era WITHIN each wave — removes the phase-locked stall of R9-R11.
//   - 1 blk/CU (128-AGPR acc), grid 384 = 8x48 bijective XCD swizzle.
// Accumulation order per output element unchanged (one MFMA per ascending
// 32-k chunk) -> bit-identical to R11; absmax 0.25 expected.

typedef _Float16 half8  __attribute__((ext_vector_type(8)));
typedef _Float16 half4v __attribute__((ext_vector_type(4)));
typedef float f32x4 __attribute__((ext_vector_type(4)));

__device__ __forceinline__ void async16(const _Float16* g, _Float16* l) {
  __builtin_amdgcn_global_load_lds(
      (const __attribute__((address_space(1))) void*)g,
      (__attribute__((address_space(3))) void*)l, 16, 0, 0);
}

struct Ptrs12 { const float* p[12]; };
struct Ptrs6  { const float* p[6];  };

// ---------------------------------------------------------------------------
// Merged prep: convert A (X|H -> fp16), convert+transpose B (x64 scale, fp16),
// build bias. Branch is block-uniform. (unchanged from R6)
__global__ void prep(const float* __restrict__ X, const float* __restrict__ H,
                     Ptrs12 w, Ptrs6 bs,
                     _Float16* __restrict__ Ahi, _Float16* __restrict__ Bhi,
                     float* __restrict__ b_all) {
  __shared__ float tile[64][65];
  const int blk = blockIdx.x;
  const int t = threadIdx.x;
  if (blk < 8192) {
    size_t base = ((size_t)blk * 256 + t) * 4;
    int k = (int)(base & 2047);
    size_t b = base >> 11;
    const float* src = (k < 1024) ? (X + b * 1024 + k) : (H + b * 1024 + (k - 1024));
    float4 v = *(const float4*)src;
    half4v hi = { (_Float16)v.x, (_Float16)v.y, (_Float16)v.z, (_Float16)v.w };
    *(half4v*)(Ahi + base) = hi;
  } else if (blk < 11264) {
    int bb = blk - 8192;
    int mat = bb >> 8;
    int tl = bb & 255;
    int tr = tl >> 4, tc = tl & 15;
    int g = mat >> 1, s = mat & 1;
    const float* src = w.p[mat];
    int col = t & 63, r0 = t >> 6;
#pragma unroll
    for (int i = 0; i < 16; i++) {
      int row = i * 4 + r0;
      tile[row][col] = src[(size_t)(tr * 64 + row) * 1024 + tc * 64 + col];
    }
    __syncthreads();
    int c2 = t >> 2, kseg = t & 3;
    half8 v0, v1;
#pragma unroll
    for (int j = 0; j < 8; j++) {
      v0[j] = (_Float16)(tile[kseg * 16 + j][c2] * 64.0f);
      v1[j] = (_Float16)(tile[kseg * 16 + 8 + j][c2] * 64.0f);
    }
    size_t n  = (size_t)g * 1024 + tc * 64 + c2;
    size_t kk = (size_t)s * 1024 + tr * 64 + kseg * 16;
    *(half8*)(Bhi + n * 2048 + kk) = v0;
    *(half8*)(Bhi + n * 2048 + kk + 8) = v1;
  } else {
    int n = (blk - 11264) * 256 + t;
    b_all[n] = bs.p[n >> 10][n & 1023];
  }
}

// ---------------------------------------------------------------------------
// GEMM: A[4096,2048] @ Bt[6144,2048]^T / 64 + bias -> pre16 (fp16, row-major).
// 256x256 tile, ring-3, split-MFMA frag-early pipeline; see header comment.

#define LGKM0 asm volatile("s_waitcnt lgkmcnt(0)" ::: "memory")

__device__ __forceinline__ void wg_barrier() {
  __builtin_amdgcn_s_barrier();
  asm volatile("" ::: "memory");
}

__global__ __launch_bounds__(512, 2) void gemm_256(
    const _Float16* __restrict__ Ah, const _Float16* __restrict__ Bh,
    const float* __restrict__ b_all, _Float16* __restrict__ pre16) {
  // 3 bufs x 16384 halfs (A 8192 + B 8192) = 96 KB. Epilogue reuses 66 KB.
  __shared__ __attribute__((aligned(16))) _Float16 lds[49152];

  // Bijective XCD swizzle: 384 blocks = 8 XCDs x 48. B-panel major within a
  // chunk (nTile constant over 16 consecutive blocks).
  const int bid = blockIdx.x;
  const int swz = (bid & 7) * 48 + (bid >> 3);
  const int nTile = swz / 16;   // 0..23
  const int mTile = swz % 16;   // 0..15

  const int t = threadIdx.x;
  const int lane = t & 63;
  const int wave = t >> 6;
  const int wm = wave >> 2, wn = wave & 3;     // 2 x 4 waves; per-wave 128x64
  const int kgrp = lane >> 4, frow = lane & 15;

  const _Float16* Abase = Ah + (size_t)mTile * 256 * 2048;
  const _Float16* Bbase = Bh + (size_t)nTile * 256 * 2048;

  f32x4 acc[8][4] = {};

  // Stage one K-tile (A 256x32 = 16KB -> 2 loads/thr; B 256x32 = 16KB -> 2).
  // LDS dest linear; 2-bit XOR slot swizzle xs = sl ^ ((r>>1)&3) folded into
  // the GLOBAL source (R11-verified conflict-free: quad = 4*(r&1) + phys-slot
  // is bijective over any 8 consecutive rows per kgrp).
  auto stage_tile = [&](int kt, int base) {
#pragma unroll
    for (int q = 0; q < 2; q++) {
      int s = q * 512 + t;
      int r = s >> 2, sl = s & 3;
      int xs = sl ^ ((r >> 1) & 3);
      async16(Abase + (size_t)r * 2048 + kt * 32 + xs * 8, lds + base + s * 8);
    }
#pragma unroll
    for (int q = 0; q < 2; q++) {
      int s = q * 512 + t;
      int r = s >> 2, sl = s & 3;
      int xs = sl ^ ((r >> 1) & 3);
      async16(Bbase + (size_t)r * 2048 + kt * 32 + xs * 8,
              lds + base + 8192 + s * 8);
    }
  };

  // Rotating ring offsets (in halfs).
  int cur = 0, nxt = 16384, nn = 32768;

  // Prologue: stage tiles 0,1 (4 loads each); vmcnt(4) -> tile0 landed;
  // then read tile0's fragments.
  stage_tile(0, cur);
  stage_tile(1, nxt);
  asm volatile("s_waitcnt vmcnt(4)" ::: "memory");
  wg_barrier();

  half8 af[8], bf[4];
  {
    const _Float16* A_ = lds + cur;
    const _Float16* B_ = lds + cur + 8192;
#pragma unroll
    for (int mi = 0; mi < 8; mi++) {
      int r = wm * 128 + mi * 16 + frow;
      af[mi] = *(const half8*)(A_ + r * 32 + ((kgrp ^ ((r >> 1) & 3)) * 8));
    }
#pragma unroll
    for (int nj = 0; nj < 4; nj++) {
      int r = wn * 64 + nj * 16 + frow;
      bf[nj] = *(const half8*)(B_ + r * 32 + ((kgrp ^ ((r >> 1) & 3)) * 8));
    }
  }

  for (int T = 0; T < 64; T++) {
    LGKM0;                                   // frags(T) landed in regs
    // Stage T+2 into buf(T+2)=buf(T-1): its last reads (frags(T-1), iter T-2)
    // drained at iter T-1's loop-top lgkm0, which precedes B(T-1); all waves
    // are past B(T-1) here -> safe.
    if (T + 2 < 64) stage_tile(T + 2, nn);

    // First half-cluster: mi 0..3 (16 MFMA).
    __builtin_amdgcn_s_setprio(1);
#pragma unroll
    for (int mi = 0; mi < 4; mi++)
#pragma unroll
      for (int nj = 0; nj < 4; nj++)
        acc[mi][nj] = __builtin_amdgcn_mfma_f32_16x16x32_f16(
            af[mi], bf[nj], acc[mi][nj], 0, 0, 0);
    __builtin_amdgcn_s_setprio(0);

    // Prove buf(T+1) (vmcnt(4): only T+2's 4 loads remain in flight).
    if (T < 62) {
      asm volatile("s_waitcnt vmcnt(4)" ::: "memory");
      wg_barrier();
    } else if (T == 62) {
      asm volatile("s_waitcnt vmcnt(0)" ::: "memory");
      wg_barrier();
    }

    // Frag-early reads for tile T+1: A[0..3] into the registers freed by the
    // first half-cluster; latency hides under the second half-cluster.
    const _Float16* An_ = lds + nxt;
    const _Float16* Bn_ = lds + nxt + 8192;
    if (T < 63) {
#pragma unroll
      for (int mi = 0; mi < 4; mi++) {
        int r = wm * 128 + mi * 16 + frow;
        af[mi] = *(const half8*)(An_ + r * 32 + ((kgrp ^ ((r >> 1) & 3)) * 8));
      }
    }

    // Second half-cluster: mi 4..7 (16 MFMA) — overlaps the reads above.
    __builtin_amdgcn_s_setprio(1);
#pragma unroll
    for (int mi = 4; mi < 8; mi++)
#pragma unroll
      for (int nj = 0; nj < 4; nj++)
        acc[mi][nj] = __builtin_amdgcn_mfma_f32_16x16x32_f16(
            af[mi], bf[nj], acc[mi][nj], 0, 0, 0);
    __builtin_amdgcn_s_setprio(0);

    // Remaining tile-T+1 frags into now-dead registers.
    if (T < 63) {
#pragma unroll
      for (int mi = 4; mi < 8; mi++) {
        int r = wm * 128 + mi * 16 + frow;
        af[mi] = *(const half8*)(An_ + r * 32 + ((kgrp ^ ((r >> 1) & 3)) * 8));
      }
#pragma unroll
      for (int nj = 0; nj < 4; nj++) {
        int r = wn * 64 + nj * 16 + frow;
        bf[nj] = *(const half8*)(Bn_ + r * 32 + ((kgrp ^ ((r >> 1) & 3)) * 8));
      }
    }

    int tmp = cur; cur = nxt; nxt = nn; nn = tmp;
  }

  // Epilogue: two 128-row passes through LDS [128][264] (66 KB), coalesced
  // half8 stores. __syncthreads() drains everything before buf reuse.
  __syncthreads();
  const float inv64 = 1.0f / 64.0f;
  const int cb = nTile * 256;
  float bias[4];
#pragma unroll
  for (int nj = 0; nj < 4; nj++)
    bias[nj] = b_all[cb + wn * 64 + nj * 16 + frow];

#pragma unroll
  for (int pass = 0; pass < 2; pass++) {
    if (wm == pass) {
#pragma unroll
      for (int mi = 0; mi < 8; mi++)
#pragma unroll
        for (int nj = 0; nj < 4; nj++) {
          int row = mi * 16 + kgrp * 4;
          int col = wn * 64 + nj * 16 + frow;
#pragma unroll
          for (int j = 0; j < 4; j++)
            lds[(row + j) * 264 + col] =
                (_Float16)(acc[mi][nj][j] * inv64 + bias[nj]);
        }
    }
    __syncthreads();
#pragma unroll
    for (int rr = 0; rr < 8; rr++) {
      int L = rr * 4096 + t * 8;
      int row = L >> 8, col = L & 255;
      half8 v = *(const half8*)(lds + row * 264 + col);
      *(half8*)(pre16 + (size_t)(mTile * 256 + pass * 128 + row) * 6144 + cb + col) = v;
    }
    __syncthreads();
  }
}

// ---------------------------------------------------------------------------
// Row softmax over zft/zit (fp16 in pre16, cols 4096..6143), p written back in
// place (fp16) + per-chunk column sums into transposed part4. (unchanged)
__global__ void softmax_partials(_Float16* __restrict__ pre16, f32x4* __restrict__ part4) {
  __shared__ float wsum[4][1024];
  int m = blockIdx.x >> 9;
  int ch = blockIdx.x & 511;
  int t = threadIdx.x;
  int wave = t >> 6, lane = t & 63;
  f32x4 colacc[4] = {};
  for (int rr = 0; rr < 2; rr++) {
    int b = ch * 8 + wave * 2 + rr;
    _Float16* row = pre16 + (size_t)b * 6144 + (4 + m) * 1024;
    f32x4 v[4];
    float mx = -3.4e38f;
#pragma unroll
    for (int j = 0; j < 4; j++) {
      half4v h = *(const half4v*)(row + lane * 4 + 256 * j);
      v[j] = f32x4{ (float)h[0], (float)h[1], (float)h[2], (float)h[3] };
      mx = fmaxf(mx, fmaxf(fmaxf(v[j][0], v[j][1]), fmaxf(v[j][2], v[j][3])));
    }
#pragma unroll
    for (int off = 32; off > 0; off >>= 1) mx = fmaxf(mx, __shfl_xor(mx, off, 64));
    float sum = 0.f;
#pragma unroll
    for (int j = 0; j < 4; j++)
#pragma unroll
      for (int q = 0; q < 4; q++) { v[j][q] = __expf(v[j][q] - mx); sum += v[j][q]; }
#pragma unroll
    for (int off = 32; off > 0; off >>= 1) sum += __shfl_xor(sum, off, 64);
    float inv = 1.f / sum;
#pragma unroll
    for (int j = 0; j < 4; j++) {
      v[j] *= inv;
      half4v h = { (_Float16)v[j][0], (_Float16)v[j][1], (_Float16)v[j][2], (_Float16)v[j][3] };
      *(half4v*)(row + lane * 4 + 256 * j) = h;
      colacc[j] += v[j];
    }
  }
#pragma unroll
  for (int j = 0; j < 4; j++)
    *(f32x4*)(&wsum[wave][lane * 4 + 256 * j]) = colacc[j];
  __syncthreads();
  f32x4 s = *(const f32x4*)(&wsum[0][t * 4]);
  s += *(const f32x4*)(&wsum[1][t * 4]);
  s += *(const f32x4*)(&wsum[2][t * 4]);
  s += *(const f32x4*)(&wsum[3][t * 4]);
  part4[((size_t)m * 256 + t) * 512 + ch] = s;
}

// Exclusive scan over 512 chunks per (m, c4-group). (unchanged)
__global__ void scan_partials(const f32x4* __restrict__ part4, f32x4* __restrict__ off4) {
  int gidx = blockIdx.x * 4 + (threadIdx.x >> 6);
  int lane = threadIdx.x & 63;
  size_t base = (size_t)gidx * 512;
  f32x4 v[8];
  f32x4 s = {};
#pragma unroll
  for (int j = 0; j < 8; j++) {
    v[j] = part4[base + lane * 8 + j];
    s += v[j];
  }
  f32x4 incl = s;
#pragma unroll
  for (int off = 1; off < 64; off <<= 1) {
    f32x4 o;
#pragma unroll
    for (int q = 0; q < 4; q++) o[q] = __shfl_up(incl[q], off, 64);
    if (lane >= off) incl += o;
  }
  f32x4 run = incl - s;
#pragma unroll
  for (int j = 0; j < 8; j++) {
    off4[base + lane * 8 + j] = run;
    run += v[j];
  }
}

// Final: gates + cumsum + cell/hidden. Fast transcendentals (R11):
// sigmoid via v_rcp_f32, tanh via (e-1)*rcp(e+1), e=__expf(2x) clamped ±15.
__device__ __forceinline__ float fast_sigmoid(float x) {
  return __builtin_amdgcn_rcpf(1.f + __expf(-x));
}
__device__ __forceinline__ float fast_tanh(float x) {
  float xc = fminf(fmaxf(x, -15.f), 15.f);
  float e = __expf(2.f * xc);
  return (e - 1.f) * __builtin_amdgcn_rcpf(e + 1.f);
}

__global__ void onlstm_final(const _Float16* __restrict__ pre16,
                             const float* __restrict__ cprev, const f32x4* __restrict__ off4,
                             float* __restrict__ out) {
  int ch = blockIdx.x;
  int c4 = threadIdx.x;
  int c = c4 * 4;
  f32x4 runf = off4[(size_t)c4 * 512 + ch];
  f32x4 runi = off4[(size_t)(256 + c4) * 512 + ch];
  for (int r = 0; r < 8; r++) {
    int b = ch * 8 + r;
    const _Float16* row = pre16 + (size_t)b * 6144;
    half4v zf = *(const half4v*)(row + c);
    half4v zi = *(const half4v*)(row + 1024 + c);
    half4v zo = *(const half4v*)(row + 2048 + c);
    half4v zc = *(const half4v*)(row + 3072 + c);
    half4v pf = *(const half4v*)(row + 4096 + c);
    half4v pi = *(const half4v*)(row + 5120 + c);
    f32x4 cp = *(const f32x4*)(cprev + (size_t)b * 1024 + c);
    f32x4 hid, cel;
#pragma unroll
    for (int q = 0; q < 4; q++) {
      runf[q] += (float)pf[q];
      runi[q] += (float)pi[q];
      float ft = runf[q], it = 1.f - runi[q];
      float f  = fast_sigmoid((float)zf[q]);
      float ii = fast_sigmoid((float)zi[q]);
      float o  = fast_sigmoid((float)zo[q]);
      float chat = fast_tanh((float)zc[q]);
      float omega = ft * it;
      float fhat = f * omega + (ft - omega);
      float ihat = ii * omega + (it - omega);
      float cell = fhat * cp[q] + ihat * chat;
      hid[q] = o * fast_tanh(cell);
      cel[q] = cell;
    }
    *(f32x4*)(out + (size_t)b * 1024 + c) = hid;
    *(f32x4*)(out + (size_t)4194304 + (size_t)b * 1024 + c) = cel;
  }
}

// ---------------------------------------------------------------------------
extern "C" void kernel_launch(void* const* d_in, const int* in_sizes, int n_in,
                              void* d_out, int out_size, void* d_ws, size_t ws_size,
                              hipStream_t stream) {
  const float* X = (const float*)d_in[0];
  const float* H = (const float*)d_in[1];
  const float* C = (const float*)d_in[2];

  char* ws = (char*)d_ws;
  _Float16* pre16 = (_Float16*)(ws);                      // 48 MB [4096][6144]
  _Float16* Ahi   = (_Float16*)(ws + 50331648);           // 16 MB
  _Float16* Bhi   = (_Float16*)(ws + 67108864);           // 24 MB
  float*    b_all = (float*)(ws + 92274688);              // 24 KB
  f32x4*    part4 = (f32x4*)(ws + 92299264);              //  4 MB
  f32x4*    off4  = (f32x4*)(ws + 96493568);              //  4 MB

  Ptrs12 w;
  for (int g = 0; g < 6; g++) {
    w.p[2 * g]     = (const float*)d_in[3 + 3 * g];
    w.p[2 * g + 1] = (const float*)d_in[4 + 3 * g];
  }
  Ptrs6 bs;
  for (int g = 0; g < 6; g++) bs.p[g] = (const float*)d_in[5 + 3 * g];

  prep<<<11288, 256, 0, stream>>>(X, H, w, bs, Ahi, Bhi, b_all);
  gemm_256<<<384, 512, 0, stream>>>(Ahi, Bhi, b_all, pre16);
  softmax_partials<<<1024, 256, 0, stream>>>(pre16, part4);
  scan_partials<<<128, 256, 0, stream>>>(part4, off4);
  onlstm_final<<<512, 256, 0, stream>>>(pre16, C, off4, (float*)d_out);
}